// Round 6
// baseline (404.919 us; speedup 1.0000x reference)
//
#include <hip/hip_runtime.h>
#include <hip/hip_bf16.h>

#define N_NODES 100000
#define N_EDGES 1600000
#define N_ROIS  400
#define HID     128
#define N_GRAPHS 512
#define NOUT    2
#define NBUCK   391      // ceil(N_NODES/256), bucket = node >> 8
#define BCAP    8192     // per-bucket edge capacity (mean 4092, 64 sigma margin)
#define ECH     4096     // edges per bucket block
#define NPW     16       // nodes per gather wave
#define NBLK_BUCKET 391  // ceil(N_EDGES/ECH)
#define NBLK_PREP   208  // 13*8*64*8 / 256
#define NBLK_GEMM   782  // ceil(N_NODES/128)

typedef __attribute__((ext_vector_type(8))) short short8;
typedef __attribute__((ext_vector_type(4))) float f32x4;

static __device__ __forceinline__ unsigned short f2bf(float f) {
  __hip_bfloat16 h = __float2bfloat16(f);   // HW RNE (v_cvt_pk_bf16_f32)
  unsigned short u;
  __builtin_memcpy(&u, &h, 2);
  return u;
}
static __device__ __forceinline__ float bf2f(unsigned short h) {
  return __uint_as_float(((unsigned)h) << 16);
}

// ==== L1 fused: blocks [0,391) bucket-append (LDS counting sort -> coalesced
//      pairs writes), [391,599) Wf fragment pack + pooled zero-init ====
__global__ __launch_bounds__(256) void prep_bucket_k(
    const int* __restrict__ row, const int* __restrict__ col,
    int* __restrict__ bcnt, unsigned int* __restrict__ pairs,
    const float* __restrict__ W, unsigned short* __restrict__ Wf,
    float* __restrict__ pooled0) {
  __shared__ int hist[NBUCK];
  __shared__ int lbase[NBUCK];            // block-local exclusive prefix
  __shared__ int adj[NBUCK];              // global in-bucket base (atomic old)
  __shared__ unsigned int spk[ECH];       // packed edges sorted by bucket
  __shared__ unsigned short sbk[ECH];     // bucket id per sorted slot
  __shared__ int sc[256];
  int t = threadIdx.x;
  if (blockIdx.x >= NBLK_BUCKET) {
    int idx = (blockIdx.x - NBLK_BUCKET) * 256 + t;
    if (idx < 13 * 8 * 64 * 8) {
      int u    = idx & 7;
      int lane = (idx >> 3) & 63;
      int nt   = (idx >> 9) & 7;
      int kk5  = idx >> 12;
      int n = nt * 16 + (lane & 15);
      int k = kk5 * 32 + (lane >> 4) * 8 + u;
      Wf[idx] = (k < N_ROIS) ? f2bf(W[k * HID + n]) : (unsigned short)0;
    }
    int z = idx * 2;                      // zero pooled (atomicMax identity)
    if (z < N_GRAPHS * HID) {
      float2 zz = {0.f, 0.f};
      *(float2*)(pooled0 + z) = zz;
    }
    return;
  }
  for (int b = t; b < NBUCK; b += 256) hist[b] = 0;
  __syncthreads();
  int e0 = blockIdx.x * ECH;
  int mtot = min(ECH, N_EDGES - e0);
  unsigned int pk[16];
  int bk[16], rk[16];
#pragma unroll
  for (int i = 0; i < 16; ++i) {
    int e = e0 + t + i * 256;
    if (e < N_EDGES) {
      int r = row[e], c = col[e];
      bk[i] = c >> 8;
      pk[i] = ((unsigned)r << 8) | (unsigned)(c & 255);
      rk[i] = atomicAdd(&hist[bk[i]], 1);   // LDS atomic: local rank
    } else bk[i] = -1;
  }
  __syncthreads();
  // exclusive scan of hist[0..391) -> lbase, in two 256-wide passes
  int v0 = hist[t];
  sc[t] = v0;
  __syncthreads();
  for (int off = 1; off < 256; off <<= 1) {
    int v = (t >= off) ? sc[t - off] : 0;
    __syncthreads();
    sc[t] += v;
    __syncthreads();
  }
  lbase[t] = sc[t] - v0;
  int tot0 = sc[255];
  __syncthreads();
  int v1 = (t < NBUCK - 256) ? hist[256 + t] : 0;
  sc[t] = v1;
  __syncthreads();
  for (int off = 1; off < 256; off <<= 1) {
    int v = (t >= off) ? sc[t - off] : 0;
    __syncthreads();
    sc[t] += v;
    __syncthreads();
  }
  if (t < NBUCK - 256) lbase[256 + t] = tot0 + sc[t] - v1;
  __syncthreads();
  // scatter into LDS in bucket-sorted order
#pragma unroll
  for (int i = 0; i < 16; ++i)
    if (bk[i] >= 0) {
      int pos = lbase[bk[i]] + rk[i];
      spk[pos] = pk[i];
      sbk[pos] = (unsigned short)bk[i];
    }
  // reserve global ranges
  for (int b = t; b < NBUCK; b += 256)
    adj[b] = (hist[b] > 0) ? atomicAdd(&bcnt[b], hist[b]) : 0;
  __syncthreads();
  // linear write: consecutive j -> consecutive dst within each bucket run
  for (int j = t; j < mtot; j += 256) {
    int b = sbk[j];
    int p = adj[b] + (j - lbase[b]);
    if (p < BCAP) pairs[(size_t)b * BCAP + p] = spk[j];
  }
}

// ==== L2 fused: blocks [0,391) per-bucket CSR build, [391,1173) GEMM ====
// GEMM branch is barrier-free: B-fragments come straight from the L2-resident
// fragment-ordered Wf (no LDS staging). LDS block = CSR struct only (35.8 KB).
__global__ __launch_bounds__(512, 4) void csr_gemm_k(
    const unsigned int* __restrict__ pairs, const int* __restrict__ bcnt,
    int* __restrict__ csr_row, int* __restrict__ offs, int* __restrict__ cnt,
    float* __restrict__ dinv,
    const float* __restrict__ x, const unsigned short* __restrict__ Wf,
    unsigned short* __restrict__ hp) {
  __shared__ __align__(16) struct {
    unsigned int ep[BCAP];               // 32 KB
    int h[256]; int sc2[256]; int cur[256];
  } c;                                   // 35.8 KB total
  int t = threadIdx.x;

  if (blockIdx.x < NBUCK) {
    // ---- CSR branch: per-node work on t<256, uniform barriers ----
    bool act = t < 256;
    int b = blockIdx.x;
    int m = min(bcnt[b], BCAP);
    size_t base = (size_t)b * BCAP;
    for (int j = t; j < m; j += 512) c.ep[j] = pairs[base + j];
    if (act) c.h[t] = 0;
    __syncthreads();
    for (int j = t; j < m; j += 512) atomicAdd(&c.h[c.ep[j] & 255u], 1);
    __syncthreads();
    int myc = act ? c.h[t] : 0;
    int mycp = (myc + 3) & ~3;          // pad slot to multiple of 4 (int4 reads)
    if (act) c.sc2[t] = mycp;
    __syncthreads();
    for (int off = 1; off < 256; off <<= 1) {
      int v = (act && t >= off) ? c.sc2[t - off] : 0;
      __syncthreads();
      if (act) c.sc2[t] += v;
      __syncthreads();
    }
    if (act) {
      int loff = c.sc2[t] - mycp;       // padded exclusive scan
      c.cur[t] = loff;
      int node = b * 256 + t;
      if (node < N_NODES) {
        cnt[node] = myc;
        offs[node] = (int)base + loff;
        dinv[node] = rsqrtf((float)(myc + 1));
      }
    }
    __syncthreads();
    for (int j = t; j < m; j += 512) {
      unsigned int e = c.ep[j];
      int pos = atomicAdd(&c.cur[e & 255u], 1);   // LDS atomic
      if (pos < BCAP) csr_row[base + pos] = (int)(e >> 8);
    }
    return;
  }

  // ---- GEMM branch: hp = bf16(x @ W); no LDS, no barriers. Each lane's
  //      B-frag is a coalesced 16 B load from Wf (106 KB, L2-resident) ----
  int lane = t & 63, wv = t >> 6;
  int mrow = lane & 15, kg = lane >> 4;
  int row0 = (blockIdx.x - NBUCK) * 128;
  int arow = row0 + wv * 16 + mrow;
  bool rowok = arow < N_NODES;
  const float* xp = x + (size_t)arow * N_ROIS;
  const short8* wp = (const short8*)Wf + lane;   // + (chunk)*64 per fragment

  f32x4 acc[8];
#pragma unroll
  for (int i = 0; i < 8; ++i) acc[i] = (f32x4){0.f, 0.f, 0.f, 0.f};

#pragma unroll
  for (int kf = 0; kf < 13; ++kf) {
    int k0 = kf * 32 + kg * 8;
    short8 a8;
    if (rowok && k0 + 8 <= N_ROIS) {
      float4 f0 = *(const float4*)(xp + k0);
      float4 f1 = *(const float4*)(xp + k0 + 4);
      a8[0] = (short)f2bf(f0.x); a8[1] = (short)f2bf(f0.y);
      a8[2] = (short)f2bf(f0.z); a8[3] = (short)f2bf(f0.w);
      a8[4] = (short)f2bf(f1.x); a8[5] = (short)f2bf(f1.y);
      a8[6] = (short)f2bf(f1.z); a8[7] = (short)f2bf(f1.w);
    } else {
#pragma unroll
      for (int v = 0; v < 8; ++v) {
        int k = k0 + v;
        float f = (rowok && k < N_ROIS) ? xp[k] : 0.f;
        a8[v] = (short)f2bf(f);
      }
    }
#pragma unroll
    for (int nt = 0; nt < 8; ++nt) {
      short8 bf = wp[(kf * 8 + nt) * 64];
      acc[nt] = __builtin_amdgcn_mfma_f32_16x16x32_bf16(a8, bf, acc[nt], 0, 0, 0);
    }
  }

#pragma unroll
  for (int r = 0; r < 4; ++r) {
    int grow = row0 + wv * 16 + kg * 4 + r;
    if (grow < N_NODES) {
      unsigned short* op = hp + (size_t)grow * HID + mrow;
#pragma unroll
      for (int nt = 0; nt < 8; ++nt) op[nt * 16] = f2bf(acc[nt][r]);
    }
  }
}

static __device__ __forceinline__ void acc8s(float* a, uint4 u, float d) {
  a[0] = fmaf(d, bf2f((unsigned short)(u.x)), a[0]);
  a[1] = fmaf(d, bf2f((unsigned short)(u.x >> 16)), a[1]);
  a[2] = fmaf(d, bf2f((unsigned short)(u.y)), a[2]);
  a[3] = fmaf(d, bf2f((unsigned short)(u.y >> 16)), a[3]);
  a[4] = fmaf(d, bf2f((unsigned short)(u.z)), a[4]);
  a[5] = fmaf(d, bf2f((unsigned short)(u.z >> 16)), a[5]);
  a[6] = fmaf(d, bf2f((unsigned short)(u.w)), a[6]);
  a[7] = fmaf(d, bf2f((unsigned short)(u.w >> 16)), a[7]);
}

// ---- aggregation (measured 93-94 us = random-fabric floor; unchanged) ----
__global__ __launch_bounds__(256) void gather_k(
    const unsigned short* __restrict__ hp, const int* __restrict__ csr_row,
    const int* __restrict__ offs, const int* __restrict__ cnt,
    const float* __restrict__ dinv, const int* __restrict__ batch,
    const float* __restrict__ bias, unsigned int* __restrict__ pooled_bits) {
  int wave = (blockIdx.x * blockDim.x + threadIdx.x) >> 6;
  int lane = threadIdx.x & 63;
  int g  = lane >> 4;        // edge-slot group 0..3
  int cg = lane & 15;        // column group: cols cg*8 .. cg*8+7
  int n0 = wave * NPW;
  if (n0 >= N_NODES) return;
  int nend = min(n0 + NPW, N_NODES);
  float bv[8];
  {
    float4 b0 = *(const float4*)(bias + cg * 8);
    float4 b1 = *(const float4*)(bias + cg * 8 + 4);
    bv[0] = b0.x; bv[1] = b0.y; bv[2] = b0.z; bv[3] = b0.w;
    bv[4] = b1.x; bv[5] = b1.y; bv[6] = b1.z; bv[7] = b1.w;
  }
  float rm[8];
#pragma unroll
  for (int k = 0; k < 8; ++k) rm[k] = 0.f;   // relu >= 0 -> 0 is identity
  int cur_g = batch[n0];

  for (int i = n0; i < nend; ++i) {
    int start = offs[i];
    int m = cnt[i];
    float di = dinv[i];
    float a[8];
#pragma unroll
    for (int k = 0; k < 8; ++k) a[k] = 0.f;
    if (g == 0) {                         // self loop: weight dinv[i]
      uint4 u = *(const uint4*)(hp + (size_t)i * HID + cg * 8);
      acc8s(a, u, di);
    }
    for (int j = 0; j < m; j += 4) {
      int4 q = *(const int4*)(csr_row + start + j);  // wave-uniform, aligned
      int s = (g == 0) ? q.x : (g == 1) ? q.y : (g == 2) ? q.z : q.w;
      if (j + g < m) {
        float dv = dinv[s];
        uint4 u = *(const uint4*)(hp + (size_t)s * HID + cg * 8);
        acc8s(a, u, dv);
      }
    }
    // butterfly: sum the 4 edge-slot groups
#pragma unroll
    for (int k = 0; k < 8; ++k) {
      a[k] += __shfl_xor(a[k], 16);
      a[k] += __shfl_xor(a[k], 32);
    }
    int gb = batch[i];
    if (gb != cur_g) {                    // wave-uniform branch
      if (lane < 16) {
#pragma unroll
        for (int k = 0; k < 8; ++k)
          atomicMax(&pooled_bits[cur_g * HID + cg * 8 + k], __float_as_uint(rm[k]));
      }
#pragma unroll
      for (int k = 0; k < 8; ++k) rm[k] = 0.f;
      cur_g = gb;
    }
#pragma unroll
    for (int k = 0; k < 8; ++k)
      rm[k] = fmaxf(rm[k], fmaxf(fmaf(di, a[k], bv[k]), 0.f));
  }
  if (lane < 16) {
#pragma unroll
    for (int k = 0; k < 8; ++k)
      atomicMax(&pooled_bits[cur_g * HID + cg * 8 + k], __float_as_uint(rm[k]));
  }
}

// ---- logits = pooled @ lin_W + lin_b ----
__global__ void logits_k(const float* __restrict__ pooled, const float* __restrict__ lin_W,
                         const float* __restrict__ lin_b, float* __restrict__ out) {
  int t = blockIdx.x * blockDim.x + threadIdx.x;
  if (t < N_GRAPHS * NOUT) {
    int g = t >> 1, o = t & 1;
    float s = lin_b[o];
    const float* pg = pooled + g * HID;
#pragma unroll 8
    for (int k = 0; k < HID; ++k) s = fmaf(pg[k], lin_W[k * NOUT + o], s);
    out[t] = s;
  }
}

extern "C" void kernel_launch(void* const* d_in, const int* in_sizes, int n_in,
                              void* d_out, int out_size, void* d_ws, size_t ws_size,
                              hipStream_t stream) {
  (void)in_sizes; (void)n_in; (void)ws_size; (void)out_size;
  const float* x     = (const float*)d_in[0];
  const int*   ei    = (const int*)d_in[1];
  const int*   row   = ei;             // sources
  const int*   col   = ei + N_EDGES;   // targets
  const int*   batch = (const int*)d_in[2];
  const float* W     = (const float*)d_in[3];
  const float* b     = (const float*)d_in[4];
  const float* lin_W = (const float*)d_in[5];
  const float* lin_b = (const float*)d_in[6];
  float* out = (float*)d_out;
  float* pooled0 = out + N_GRAPHS * NOUT;

  // workspace layout, 52.5 MB total (hp de-aliased from pairs for L2 fusion)
  char* ws = (char*)d_ws;
  int*   bcnt    = (int*)(ws + 0);               //   4,096 B (391 used)
  int*   offs    = (int*)(ws + 4096);            // 400,000 B
  int*   cnt     = (int*)(ws + 404096);          // 400,000 B
  float* dinv    = (float*)(ws + 804096);        // 400,000 B
  unsigned short* Wf = (unsigned short*)(ws + 1204096);   // 106,496 B (frag order)
  int*   csr_row = (int*)(ws + 1310720);         // 391*8192*4 = 12,812,288 B
  unsigned int* pairs = (unsigned int*)(ws + 14123008);   // 12,812,288 B
  unsigned short* hp  = (unsigned short*)(ws + 26935296); // 25,600,000 B

  hipMemsetAsync(bcnt, 0, NBUCK * sizeof(int), stream);

  // L1: bucket-append || Wf pack + pooled zero (out memset folded in here)
  prep_bucket_k<<<NBLK_BUCKET + NBLK_PREP, 256, 0, stream>>>(
      row, col, bcnt, pairs, W, Wf, pooled0);
  // L2: CSR build (391 blocks) || barrier-free GEMM (782 blocks) on one grid
  csr_gemm_k<<<NBUCK + NBLK_GEMM, 512, 0, stream>>>(
      pairs, bcnt, csr_row, offs, cnt, dinv, x, Wf, hp);
  // L3: gather (random-fabric floor ~94 us)
  {
    int waves = (N_NODES + NPW - 1) / NPW;             // 6250
    int blocks = (waves * 64 + 255) / 256;             // 1563
    gather_k<<<blocks, 256, 0, stream>>>(
        hp, csr_row, offs, cnt, dinv, batch, b,
        (unsigned int*)pooled0);
  }
  logits_k<<<(N_GRAPHS * NOUT + 255) / 256, 256, 0, stream>>>(
      pooled0, lin_W, lin_b, out);
}

// Round 7
// 389.981 us; speedup vs baseline: 1.0383x; 1.0383x over previous
//
#include <hip/hip_runtime.h>
#include <hip/hip_bf16.h>

#define N_NODES 100000
#define N_EDGES 1600000
#define N_ROIS  400
#define HID     128
#define N_GRAPHS 512
#define NOUT    2
#define NBUCK   391      // ceil(N_NODES/256), bucket = node >> 8
#define BCAP    8192     // per-bucket edge capacity (mean 4092, 64 sigma margin)
#define ECH     4096     // edges per bucket block
#define NPW     16       // nodes per gather wave
#define NBLK_BUCKET 391  // ceil(N_EDGES/ECH)
#define NBLK_PREP   208  // 13*8*64*8 / 256
#define NBLK_GEMM   782  // ceil(N_NODES/128)

typedef __attribute__((ext_vector_type(8))) short short8;
typedef __attribute__((ext_vector_type(4))) float f32x4;

static __device__ __forceinline__ unsigned short f2bf(float f) {
  __hip_bfloat16 h = __float2bfloat16(f);   // HW RNE
  unsigned short u;
  __builtin_memcpy(&u, &h, 2);
  return u;
}
static __device__ __forceinline__ float bf2f(unsigned short h) {
  return __uint_as_float(((unsigned)h) << 16);
}

static __device__ __forceinline__ void gload_lds16(const unsigned short* g, short* l) {
  __builtin_amdgcn_global_load_lds(
      (const __attribute__((address_space(1))) void*)g,
      (__attribute__((address_space(3))) void*)l, 16, 0, 0);
}

// ==== L1 fused: blocks [0,391) bucket-append (LDS counting sort -> coalesced
//      pairs writes), [391,599) Wf fragment pack + pooled zero-init ====
__global__ __launch_bounds__(256) void prep_bucket_k(
    const int* __restrict__ row, const int* __restrict__ col,
    int* __restrict__ bcnt, unsigned int* __restrict__ pairs,
    const float* __restrict__ W, unsigned short* __restrict__ Wf,
    float* __restrict__ pooled0) {
  __shared__ int hist[NBUCK];
  __shared__ int lbase[NBUCK];            // block-local exclusive prefix
  __shared__ int adj[NBUCK];              // global in-bucket base (atomic old)
  __shared__ unsigned int spk[ECH];       // packed edges sorted by bucket
  __shared__ unsigned short sbk[ECH];     // bucket id per sorted slot
  __shared__ int sc[256];
  int t = threadIdx.x;
  if (blockIdx.x >= NBLK_BUCKET) {
    int idx = (blockIdx.x - NBLK_BUCKET) * 256 + t;
    if (idx < 13 * 8 * 64 * 8) {
      int u    = idx & 7;
      int lane = (idx >> 3) & 63;
      int nt   = (idx >> 9) & 7;
      int kk5  = idx >> 12;
      int n = nt * 16 + (lane & 15);
      int k = kk5 * 32 + (lane >> 4) * 8 + u;
      Wf[idx] = (k < N_ROIS) ? f2bf(W[k * HID + n]) : (unsigned short)0;
    }
    int z = idx * 2;                      // zero pooled (atomicMax identity)
    if (z < N_GRAPHS * HID) {
      float2 zz = {0.f, 0.f};
      *(float2*)(pooled0 + z) = zz;
    }
    return;
  }
  for (int b = t; b < NBUCK; b += 256) hist[b] = 0;
  __syncthreads();
  int e0 = blockIdx.x * ECH;
  int mtot = min(ECH, N_EDGES - e0);
  unsigned int pk[16];
  int bk[16], rk[16];
#pragma unroll
  for (int i = 0; i < 16; ++i) {
    int e = e0 + t + i * 256;
    if (e < N_EDGES) {
      int r = row[e], c = col[e];
      bk[i] = c >> 8;
      pk[i] = ((unsigned)r << 8) | (unsigned)(c & 255);
      rk[i] = atomicAdd(&hist[bk[i]], 1);   // LDS atomic: local rank
    } else bk[i] = -1;
  }
  __syncthreads();
  // exclusive scan of hist[0..391) -> lbase, in two 256-wide passes
  int v0 = hist[t];
  sc[t] = v0;
  __syncthreads();
  for (int off = 1; off < 256; off <<= 1) {
    int v = (t >= off) ? sc[t - off] : 0;
    __syncthreads();
    sc[t] += v;
    __syncthreads();
  }
  lbase[t] = sc[t] - v0;
  int tot0 = sc[255];
  __syncthreads();
  int v1 = (t < NBUCK - 256) ? hist[256 + t] : 0;
  sc[t] = v1;
  __syncthreads();
  for (int off = 1; off < 256; off <<= 1) {
    int v = (t >= off) ? sc[t - off] : 0;
    __syncthreads();
    sc[t] += v;
    __syncthreads();
  }
  if (t < NBUCK - 256) lbase[256 + t] = tot0 + sc[t] - v1;
  __syncthreads();
  // scatter into LDS in bucket-sorted order
#pragma unroll
  for (int i = 0; i < 16; ++i)
    if (bk[i] >= 0) {
      int pos = lbase[bk[i]] + rk[i];
      spk[pos] = pk[i];
      sbk[pos] = (unsigned short)bk[i];
    }
  // reserve global ranges
  for (int b = t; b < NBUCK; b += 256)
    adj[b] = (hist[b] > 0) ? atomicAdd(&bcnt[b], hist[b]) : 0;
  __syncthreads();
  // linear write: consecutive j -> consecutive dst within each bucket run
  for (int j = t; j < mtot; j += 256) {
    int b = sbk[j];
    int p = adj[b] + (j - lbase[b]);
    if (p < BCAP) pairs[(size_t)b * BCAP + p] = spk[j];
  }
}

// ==== L2 fused: blocks [0,391) per-bucket CSR build, [391,1173) GEMM ====
// GEMM stages Wf in 4 phases of <=32 KB via global_load_lds; union with the
// CSR struct stays 35.8 KB -> 4 blocks/CU (32 waves) at launch_bounds(512,8).
__global__ __launch_bounds__(512, 8) void csr_gemm_k(
    const unsigned int* __restrict__ pairs, const int* __restrict__ bcnt,
    int* __restrict__ csr_row, int* __restrict__ offs, int* __restrict__ cnt,
    float* __restrict__ dinv,
    const float* __restrict__ x, const unsigned short* __restrict__ Wf,
    unsigned short* __restrict__ hp) {
  __shared__ __align__(16) union {
    struct {
      unsigned int ep[BCAP];             // 32 KB
      int h[256]; int sc2[256]; int cur[256];
    } c;                                 // 35.8 KB
    short Bs[16384];                     // 32 KB (4 K-steps x 8 nt x 1 KB)
  } u;
  int t = threadIdx.x;

  if (blockIdx.x < NBUCK) {
    // ---- CSR branch: per-node work on t<256, uniform barriers ----
    bool act = t < 256;
    int b = blockIdx.x;
    int m = min(bcnt[b], BCAP);
    size_t base = (size_t)b * BCAP;
    for (int j = t; j < m; j += 512) u.c.ep[j] = pairs[base + j];
    if (act) u.c.h[t] = 0;
    __syncthreads();
    for (int j = t; j < m; j += 512) atomicAdd(&u.c.h[u.c.ep[j] & 255u], 1);
    __syncthreads();
    int myc = act ? u.c.h[t] : 0;
    int mycp = (myc + 3) & ~3;          // pad slot to multiple of 4 (int4 reads)
    if (act) u.c.sc2[t] = mycp;
    __syncthreads();
    for (int off = 1; off < 256; off <<= 1) {
      int v = (act && t >= off) ? u.c.sc2[t - off] : 0;
      __syncthreads();
      if (act) u.c.sc2[t] += v;
      __syncthreads();
    }
    if (act) {
      int loff = u.c.sc2[t] - mycp;     // padded exclusive scan
      u.c.cur[t] = loff;
      int node = b * 256 + t;
      if (node < N_NODES) {
        cnt[node] = myc;
        offs[node] = (int)base + loff;
        dinv[node] = rsqrtf((float)(myc + 1));
      }
    }
    __syncthreads();
    for (int j = t; j < m; j += 512) {
      unsigned int e = u.c.ep[j];
      int pos = atomicAdd(&u.c.cur[e & 255u], 1);   // LDS atomic
      if (pos < BCAP) csr_row[base + pos] = (int)(e >> 8);
    }
    return;
  }

  // ---- GEMM branch: hp = bf16(x @ W), 4-phase LDS staging ----
  int lane = t & 63, wv = t >> 6;
  int mrow = lane & 15, kg = lane >> 4;
  int row0 = (blockIdx.x - NBUCK) * 128;
  int arow = row0 + wv * 16 + mrow;
  bool rowok = arow < N_NODES;
  const float* xp = x + (size_t)arow * N_ROIS;

  f32x4 acc[8];
#pragma unroll
  for (int i = 0; i < 8; ++i) acc[i] = (f32x4){0.f, 0.f, 0.f, 0.f};

  const int pk0[4] = {0, 4, 7, 10};     // first K-step of each phase
  const int pnk[4] = {4, 3, 3, 3};      // K-steps per phase (chunks/wave = pnk)

#pragma unroll
  for (int ph = 0; ph < 4; ++ph) {
    int cbase = pk0[ph] * 8;            // global 1KB-chunk base
#pragma unroll
    for (int c = 0; c < pnk[ph]; ++c) {
      int ch = wv * pnk[ph] + c;        // local chunk 0..8*pnk-1
      gload_lds16(Wf + ((size_t)cbase + ch) * 512 + lane * 8, &u.Bs[ch * 512]);
    }
    asm volatile("s_waitcnt vmcnt(0)" ::: "memory");
    __syncthreads();
#pragma unroll
    for (int kfl = 0; kfl < pnk[ph]; ++kfl) {
      int kf = pk0[ph] + kfl;
      int k0 = kf * 32 + kg * 8;
      short8 a8;
      if (rowok && k0 + 8 <= N_ROIS) {
        float4 f0 = *(const float4*)(xp + k0);
        float4 f1 = *(const float4*)(xp + k0 + 4);
        a8[0] = (short)f2bf(f0.x); a8[1] = (short)f2bf(f0.y);
        a8[2] = (short)f2bf(f0.z); a8[3] = (short)f2bf(f0.w);
        a8[4] = (short)f2bf(f1.x); a8[5] = (short)f2bf(f1.y);
        a8[6] = (short)f2bf(f1.z); a8[7] = (short)f2bf(f1.w);
      } else {
#pragma unroll
        for (int v = 0; v < 8; ++v) {
          int k = k0 + v;
          float f = (rowok && k < N_ROIS) ? xp[k] : 0.f;
          a8[v] = (short)f2bf(f);
        }
      }
#pragma unroll
      for (int nt = 0; nt < 8; ++nt) {
        short8 bf = *(const short8*)&u.Bs[(kfl * 8 + nt) * 512 + lane * 8];
        acc[nt] = __builtin_amdgcn_mfma_f32_16x16x32_bf16(a8, bf, acc[nt], 0, 0, 0);
      }
    }
    __syncthreads();
  }

#pragma unroll
  for (int r = 0; r < 4; ++r) {
    int grow = row0 + wv * 16 + kg * 4 + r;
    if (grow < N_NODES) {
      unsigned short* op = hp + (size_t)grow * HID + mrow;
#pragma unroll
      for (int nt = 0; nt < 8; ++nt) op[nt * 16] = f2bf(acc[nt][r]);
    }
  }
}

static __device__ __forceinline__ void acc8s(float* a, uint4 u, float d) {
  a[0] = fmaf(d, bf2f((unsigned short)(u.x)), a[0]);
  a[1] = fmaf(d, bf2f((unsigned short)(u.x >> 16)), a[1]);
  a[2] = fmaf(d, bf2f((unsigned short)(u.y)), a[2]);
  a[3] = fmaf(d, bf2f((unsigned short)(u.y >> 16)), a[3]);
  a[4] = fmaf(d, bf2f((unsigned short)(u.z)), a[4]);
  a[5] = fmaf(d, bf2f((unsigned short)(u.z >> 16)), a[5]);
  a[6] = fmaf(d, bf2f((unsigned short)(u.w)), a[6]);
  a[7] = fmaf(d, bf2f((unsigned short)(u.w >> 16)), a[7]);
}

// ---- aggregation (measured 93-94 us = random-fabric floor; unchanged) ----
__global__ __launch_bounds__(256) void gather_k(
    const unsigned short* __restrict__ hp, const int* __restrict__ csr_row,
    const int* __restrict__ offs, const int* __restrict__ cnt,
    const float* __restrict__ dinv, const int* __restrict__ batch,
    const float* __restrict__ bias, unsigned int* __restrict__ pooled_bits) {
  int wave = (blockIdx.x * blockDim.x + threadIdx.x) >> 6;
  int lane = threadIdx.x & 63;
  int g  = lane >> 4;        // edge-slot group 0..3
  int cg = lane & 15;        // column group: cols cg*8 .. cg*8+7
  int n0 = wave * NPW;
  if (n0 >= N_NODES) return;
  int nend = min(n0 + NPW, N_NODES);
  float bv[8];
  {
    float4 b0 = *(const float4*)(bias + cg * 8);
    float4 b1 = *(const float4*)(bias + cg * 8 + 4);
    bv[0] = b0.x; bv[1] = b0.y; bv[2] = b0.z; bv[3] = b0.w;
    bv[4] = b1.x; bv[5] = b1.y; bv[6] = b1.z; bv[7] = b1.w;
  }
  float rm[8];
#pragma unroll
  for (int k = 0; k < 8; ++k) rm[k] = 0.f;   // relu >= 0 -> 0 is identity
  int cur_g = batch[n0];

  for (int i = n0; i < nend; ++i) {
    int start = offs[i];
    int m = cnt[i];
    float di = dinv[i];
    float a[8];
#pragma unroll
    for (int k = 0; k < 8; ++k) a[k] = 0.f;
    if (g == 0) {                         // self loop: weight dinv[i]
      uint4 u = *(const uint4*)(hp + (size_t)i * HID + cg * 8);
      acc8s(a, u, di);
    }
    for (int j = 0; j < m; j += 4) {
      int4 q = *(const int4*)(csr_row + start + j);  // wave-uniform, aligned
      int s = (g == 0) ? q.x : (g == 1) ? q.y : (g == 2) ? q.z : q.w;
      if (j + g < m) {
        float dv = dinv[s];
        uint4 u = *(const uint4*)(hp + (size_t)s * HID + cg * 8);
        acc8s(a, u, dv);
      }
    }
    // butterfly: sum the 4 edge-slot groups
#pragma unroll
    for (int k = 0; k < 8; ++k) {
      a[k] += __shfl_xor(a[k], 16);
      a[k] += __shfl_xor(a[k], 32);
    }
    int gb = batch[i];
    if (gb != cur_g) {                    // wave-uniform branch
      if (lane < 16) {
#pragma unroll
        for (int k = 0; k < 8; ++k)
          atomicMax(&pooled_bits[cur_g * HID + cg * 8 + k], __float_as_uint(rm[k]));
      }
#pragma unroll
      for (int k = 0; k < 8; ++k) rm[k] = 0.f;
      cur_g = gb;
    }
#pragma unroll
    for (int k = 0; k < 8; ++k)
      rm[k] = fmaxf(rm[k], fmaxf(fmaf(di, a[k], bv[k]), 0.f));
  }
  if (lane < 16) {
#pragma unroll
    for (int k = 0; k < 8; ++k)
      atomicMax(&pooled_bits[cur_g * HID + cg * 8 + k], __float_as_uint(rm[k]));
  }
}

// ---- logits = pooled @ lin_W + lin_b ----
__global__ void logits_k(const float* __restrict__ pooled, const float* __restrict__ lin_W,
                         const float* __restrict__ lin_b, float* __restrict__ out) {
  int t = blockIdx.x * blockDim.x + threadIdx.x;
  if (t < N_GRAPHS * NOUT) {
    int g = t >> 1, o = t & 1;
    float s = lin_b[o];
    const float* pg = pooled + g * HID;
#pragma unroll 8
    for (int k = 0; k < HID; ++k) s = fmaf(pg[k], lin_W[k * NOUT + o], s);
    out[t] = s;
  }
}

extern "C" void kernel_launch(void* const* d_in, const int* in_sizes, int n_in,
                              void* d_out, int out_size, void* d_ws, size_t ws_size,
                              hipStream_t stream) {
  (void)in_sizes; (void)n_in; (void)ws_size; (void)out_size;
  const float* x     = (const float*)d_in[0];
  const int*   ei    = (const int*)d_in[1];
  const int*   row   = ei;             // sources
  const int*   col   = ei + N_EDGES;   // targets
  const int*   batch = (const int*)d_in[2];
  const float* W     = (const float*)d_in[3];
  const float* b     = (const float*)d_in[4];
  const float* lin_W = (const float*)d_in[5];
  const float* lin_b = (const float*)d_in[6];
  float* out = (float*)d_out;
  float* pooled0 = out + N_GRAPHS * NOUT;

  // workspace layout, 52.5 MB total (hp de-aliased from pairs for L2 fusion)
  char* ws = (char*)d_ws;
  int*   bcnt    = (int*)(ws + 0);               //   4,096 B (391 used)
  int*   offs    = (int*)(ws + 4096);            // 400,000 B
  int*   cnt     = (int*)(ws + 404096);          // 400,000 B
  float* dinv    = (float*)(ws + 804096);        // 400,000 B
  unsigned short* Wf = (unsigned short*)(ws + 1204096);   // 106,496 B (frag order)
  int*   csr_row = (int*)(ws + 1310720);         // 391*8192*4 = 12,812,288 B
  unsigned int* pairs = (unsigned int*)(ws + 14123008);   // 12,812,288 B
  unsigned short* hp  = (unsigned short*)(ws + 26935296); // 25,600,000 B

  hipMemsetAsync(bcnt, 0, NBUCK * sizeof(int), stream);

  // L1: bucket-append || Wf pack + pooled zero (out memset folded in here)
  prep_bucket_k<<<NBLK_BUCKET + NBLK_PREP, 256, 0, stream>>>(
      row, col, bcnt, pairs, W, Wf, pooled0);
  // L2: CSR build (391 blocks) || 4-phase staged GEMM (782 blocks), 4 blk/CU
  csr_gemm_k<<<NBUCK + NBLK_GEMM, 512, 0, stream>>>(
      pairs, bcnt, csr_row, offs, cnt, dinv, x, Wf, hp);
  // L3: gather (random-fabric floor ~94 us)
  {
    int waves = (N_NODES + NPW - 1) / NPW;             // 6250
    int blocks = (waves * 64 + 255) / 256;             // 1563
    gather_k<<<blocks, 256, 0, stream>>>(
        hp, csr_row, offs, cnt, dinv, batch, b,
        (unsigned int*)pooled0);
  }
  logits_k<<<(N_GRAPHS * NOUT + 255) / 256, 256, 0, stream>>>(
      pooled0, lin_W, lin_b, out);
}

// Round 8
// 386.443 us; speedup vs baseline: 1.0478x; 1.0092x over previous
//
#include <hip/hip_runtime.h>
#include <hip/hip_bf16.h>

#define N_NODES 100000
#define N_EDGES 1600000
#define N_ROIS  400
#define HID     128
#define N_GRAPHS 512
#define NOUT    2
#define NBUCK   391      // ceil(N_NODES/256), bucket = node >> 8
#define BCAP    8192     // per-bucket edge capacity (mean 4092, 64 sigma margin)
#define ECH     4096     // edges per bucket block
#define NPW     16       // nodes per gather wave
#define NBLK_BUCKET 391  // ceil(N_EDGES/ECH)
#define NBLK_PREP   208  // 13*8*64*8 / 256
#define NBLK_XCONV  20313 // ceil(100000*52/256): x fp32 -> xb bf16 [416]/row
#define NBLK_GEMM   782  // ceil(N_NODES/128)
#define XROW 416         // padded bf16 row length (13*32), zeros for k>=400

typedef __attribute__((ext_vector_type(8))) short short8;
typedef __attribute__((ext_vector_type(4))) float f32x4;

static __device__ __forceinline__ unsigned short f2bf(float f) {
  __hip_bfloat16 h = __float2bfloat16(f);   // HW RNE
  unsigned short u;
  __builtin_memcpy(&u, &h, 2);
  return u;
}
static __device__ __forceinline__ float bf2f(unsigned short h) {
  return __uint_as_float(((unsigned)h) << 16);
}

static __device__ __forceinline__ void gload_lds16(const unsigned short* g, short* l) {
  __builtin_amdgcn_global_load_lds(
      (const __attribute__((address_space(1))) void*)g,
      (__attribute__((address_space(3))) void*)l, 16, 0, 0);
}

// ==== L1 fused: [0,391) bucket-append (LDS sort -> coalesced pairs writes),
//      [391,599) Wf fragment pack + pooled zero, [599,20912) x -> xb bf16 ====
__global__ __launch_bounds__(256) void prep_bucket_k(
    const int* __restrict__ row, const int* __restrict__ col,
    int* __restrict__ bcnt, unsigned int* __restrict__ pairs,
    const float* __restrict__ W, unsigned short* __restrict__ Wf,
    const float* __restrict__ x, unsigned short* __restrict__ xb,
    float* __restrict__ pooled0) {
  __shared__ int hist[NBUCK];
  __shared__ int lbase[NBUCK];
  __shared__ int adj[NBUCK];
  __shared__ unsigned int spk[ECH];
  __shared__ unsigned short sbk[ECH];
  __shared__ int sc[256];
  int t = threadIdx.x;
  if (blockIdx.x >= NBLK_BUCKET + NBLK_PREP) {
    // ---- x convert branch: pure streaming, bit-identical RNE ----
    int idx = (blockIdx.x - NBLK_BUCKET - NBLK_PREP) * 256 + t;
    int n = idx / 52, rem = idx - n * 52;
    if (n < N_NODES) {
      int k0 = rem * 8;
      short8 v;
      if (k0 + 8 <= N_ROIS) {
        const float* xp = x + (size_t)n * N_ROIS + k0;
        float4 f0 = *(const float4*)xp;
        float4 f1 = *(const float4*)(xp + 4);
        v[0] = (short)f2bf(f0.x); v[1] = (short)f2bf(f0.y);
        v[2] = (short)f2bf(f0.z); v[3] = (short)f2bf(f0.w);
        v[4] = (short)f2bf(f1.x); v[5] = (short)f2bf(f1.y);
        v[6] = (short)f2bf(f1.z); v[7] = (short)f2bf(f1.w);
      } else {
        v = (short8){0, 0, 0, 0, 0, 0, 0, 0};   // K-pad: never NaN
      }
      *(short8*)(xb + (size_t)n * XROW + k0) = v;
    }
    return;
  }
  if (blockIdx.x >= NBLK_BUCKET) {
    int idx = (blockIdx.x - NBLK_BUCKET) * 256 + t;
    if (idx < 13 * 8 * 64 * 8) {
      int u    = idx & 7;
      int lane = (idx >> 3) & 63;
      int nt   = (idx >> 9) & 7;
      int kk5  = idx >> 12;
      int n = nt * 16 + (lane & 15);
      int k = kk5 * 32 + (lane >> 4) * 8 + u;
      Wf[idx] = (k < N_ROIS) ? f2bf(W[k * HID + n]) : (unsigned short)0;
    }
    int z = idx * 2;                      // zero pooled (atomicMax identity)
    if (z < N_GRAPHS * HID) {
      float2 zz = {0.f, 0.f};
      *(float2*)(pooled0 + z) = zz;
    }
    return;
  }
  for (int b = t; b < NBUCK; b += 256) hist[b] = 0;
  __syncthreads();
  int e0 = blockIdx.x * ECH;
  int mtot = min(ECH, N_EDGES - e0);
  unsigned int pk[16];
  int bk[16], rk[16];
#pragma unroll
  for (int i = 0; i < 16; ++i) {
    int e = e0 + t + i * 256;
    if (e < N_EDGES) {
      int r = row[e], c = col[e];
      bk[i] = c >> 8;
      pk[i] = ((unsigned)r << 8) | (unsigned)(c & 255);
      rk[i] = atomicAdd(&hist[bk[i]], 1);   // LDS atomic: local rank
    } else bk[i] = -1;
  }
  __syncthreads();
  // exclusive scan of hist[0..391) -> lbase, two 256-wide passes
  int v0 = hist[t];
  sc[t] = v0;
  __syncthreads();
  for (int off = 1; off < 256; off <<= 1) {
    int v = (t >= off) ? sc[t - off] : 0;
    __syncthreads();
    sc[t] += v;
    __syncthreads();
  }
  lbase[t] = sc[t] - v0;
  int tot0 = sc[255];
  __syncthreads();
  int v1 = (t < NBUCK - 256) ? hist[256 + t] : 0;
  sc[t] = v1;
  __syncthreads();
  for (int off = 1; off < 256; off <<= 1) {
    int v = (t >= off) ? sc[t - off] : 0;
    __syncthreads();
    sc[t] += v;
    __syncthreads();
  }
  if (t < NBUCK - 256) lbase[256 + t] = tot0 + sc[t] - v1;
  __syncthreads();
#pragma unroll
  for (int i = 0; i < 16; ++i)
    if (bk[i] >= 0) {
      int pos = lbase[bk[i]] + rk[i];
      spk[pos] = pk[i];
      sbk[pos] = (unsigned short)bk[i];
    }
  for (int b = t; b < NBUCK; b += 256)
    adj[b] = (hist[b] > 0) ? atomicAdd(&bcnt[b], hist[b]) : 0;
  __syncthreads();
  for (int j = t; j < mtot; j += 256) {
    int b = sbk[j];
    int p = adj[b] + (j - lbase[b]);
    if (p < BCAP) pairs[(size_t)b * BCAP + p] = spk[j];
  }
}

// ==== L2 fused: blocks [0,391) per-bucket CSR build, [391,1173) GEMM ====
// GEMM: A-side = 13 independent bf16 fragment loads from xb prefetched into
// 52 VGPRs (kills the serial fp32-x latency chain); Wf staged 4x32KB phases.
__global__ __launch_bounds__(512, 4) void csr_gemm_k(
    const unsigned int* __restrict__ pairs, const int* __restrict__ bcnt,
    int* __restrict__ csr_row, int* __restrict__ offs, int* __restrict__ cnt,
    float* __restrict__ dinv,
    const unsigned short* __restrict__ xb, const unsigned short* __restrict__ Wf,
    unsigned short* __restrict__ hp) {
  __shared__ __align__(16) union {
    struct {
      unsigned int ep[BCAP];             // 32 KB
      int h[256]; int sc2[256]; int cur[256];
    } c;                                 // 35.8 KB
    short Bs[16384];                     // 32 KB (<=4 K-steps x 8 nt x 1 KB)
  } u;
  int t = threadIdx.x;

  if (blockIdx.x < NBUCK) {
    // ---- CSR branch: per-node work on t<256, uniform barriers ----
    bool act = t < 256;
    int b = blockIdx.x;
    int m = min(bcnt[b], BCAP);
    size_t base = (size_t)b * BCAP;
    for (int j = t; j < m; j += 512) u.c.ep[j] = pairs[base + j];
    if (act) u.c.h[t] = 0;
    __syncthreads();
    for (int j = t; j < m; j += 512) atomicAdd(&u.c.h[u.c.ep[j] & 255u], 1);
    __syncthreads();
    int myc = act ? u.c.h[t] : 0;
    int mycp = (myc + 3) & ~3;          // pad slot to multiple of 4 (int4 reads)
    if (act) u.c.sc2[t] = mycp;
    __syncthreads();
    for (int off = 1; off < 256; off <<= 1) {
      int v = (act && t >= off) ? u.c.sc2[t - off] : 0;
      __syncthreads();
      if (act) u.c.sc2[t] += v;
      __syncthreads();
    }
    if (act) {
      int loff = u.c.sc2[t] - mycp;
      u.c.cur[t] = loff;
      int node = b * 256 + t;
      if (node < N_NODES) {
        cnt[node] = myc;
        offs[node] = (int)base + loff;
        dinv[node] = rsqrtf((float)(myc + 1));
      }
    }
    __syncthreads();
    for (int j = t; j < m; j += 512) {
      unsigned int e = u.c.ep[j];
      int pos = atomicAdd(&u.c.cur[e & 255u], 1);   // LDS atomic
      if (pos < BCAP) csr_row[base + pos] = (int)(e >> 8);
    }
    return;
  }

  // ---- GEMM branch: hp = bf16-matmul(xb, Wf) ----
  int lane = t & 63, wv = t >> 6;
  int mrow = lane & 15, kg = lane >> 4;
  int row0 = (blockIdx.x - NBUCK) * 128;
  int arow = row0 + wv * 16 + mrow;
  const unsigned short* xr = xb + (size_t)arow * XROW + kg * 8;

  // prefetch ALL 13 A-fragments (13 independent dwordx4, 52 VGPRs).
  // OOB rows read workspace garbage; it stays confined to D-rows that the
  // epilogue guard never writes (MFMA row mapping), so no NaN escapes.
  short8 xa[13];
#pragma unroll
  for (int kf = 0; kf < 13; ++kf)
    xa[kf] = *(const short8*)(xr + kf * 32);

  f32x4 acc[8];
#pragma unroll
  for (int i = 0; i < 8; ++i) acc[i] = (f32x4){0.f, 0.f, 0.f, 0.f};

  const int pk0[4] = {0, 4, 7, 10};     // first K-step of each phase
  const int pnk[4] = {4, 3, 3, 3};      // K-steps per phase

#pragma unroll
  for (int ph = 0; ph < 4; ++ph) {
    int cbase = pk0[ph] * 8;
#pragma unroll
    for (int c = 0; c < pnk[ph]; ++c) {
      int ch = wv * pnk[ph] + c;
      gload_lds16(Wf + ((size_t)cbase + ch) * 512 + lane * 8, &u.Bs[ch * 512]);
    }
    asm volatile("s_waitcnt vmcnt(0)" ::: "memory");
    __syncthreads();
#pragma unroll
    for (int kfl = 0; kfl < pnk[ph]; ++kfl) {
      int kf = pk0[ph] + kfl;           // compile-time after unroll
#pragma unroll
      for (int nt = 0; nt < 8; ++nt) {
        short8 bf = *(const short8*)&u.Bs[(kfl * 8 + nt) * 512 + lane * 8];
        acc[nt] = __builtin_amdgcn_mfma_f32_16x16x32_bf16(xa[kf], bf, acc[nt], 0, 0, 0);
      }
    }
    __syncthreads();
  }

#pragma unroll
  for (int r = 0; r < 4; ++r) {
    int grow = row0 + wv * 16 + kg * 4 + r;
    if (grow < N_NODES) {
      unsigned short* op = hp + (size_t)grow * HID + mrow;
#pragma unroll
      for (int nt = 0; nt < 8; ++nt) op[nt * 16] = f2bf(acc[nt][r]);
    }
  }
}

static __device__ __forceinline__ void acc8s(float* a, uint4 u, float d) {
  a[0] = fmaf(d, bf2f((unsigned short)(u.x)), a[0]);
  a[1] = fmaf(d, bf2f((unsigned short)(u.x >> 16)), a[1]);
  a[2] = fmaf(d, bf2f((unsigned short)(u.y)), a[2]);
  a[3] = fmaf(d, bf2f((unsigned short)(u.y >> 16)), a[3]);
  a[4] = fmaf(d, bf2f((unsigned short)(u.z)), a[4]);
  a[5] = fmaf(d, bf2f((unsigned short)(u.z >> 16)), a[5]);
  a[6] = fmaf(d, bf2f((unsigned short)(u.w)), a[6]);
  a[7] = fmaf(d, bf2f((unsigned short)(u.w >> 16)), a[7]);
}

// ---- aggregation (measured 93-95 us = random-fabric floor; unchanged) ----
__global__ __launch_bounds__(256) void gather_k(
    const unsigned short* __restrict__ hp, const int* __restrict__ csr_row,
    const int* __restrict__ offs, const int* __restrict__ cnt,
    const float* __restrict__ dinv, const int* __restrict__ batch,
    const float* __restrict__ bias, unsigned int* __restrict__ pooled_bits) {
  int wave = (blockIdx.x * blockDim.x + threadIdx.x) >> 6;
  int lane = threadIdx.x & 63;
  int g  = lane >> 4;        // edge-slot group 0..3
  int cg = lane & 15;        // column group: cols cg*8 .. cg*8+7
  int n0 = wave * NPW;
  if (n0 >= N_NODES) return;
  int nend = min(n0 + NPW, N_NODES);
  float bv[8];
  {
    float4 b0 = *(const float4*)(bias + cg * 8);
    float4 b1 = *(const float4*)(bias + cg * 8 + 4);
    bv[0] = b0.x; bv[1] = b0.y; bv[2] = b0.z; bv[3] = b0.w;
    bv[4] = b1.x; bv[5] = b1.y; bv[6] = b1.z; bv[7] = b1.w;
  }
  float rm[8];
#pragma unroll
  for (int k = 0; k < 8; ++k) rm[k] = 0.f;   // relu >= 0 -> 0 is identity
  int cur_g = batch[n0];

  for (int i = n0; i < nend; ++i) {
    int start = offs[i];
    int m = cnt[i];
    float di = dinv[i];
    float a[8];
#pragma unroll
    for (int k = 0; k < 8; ++k) a[k] = 0.f;
    if (g == 0) {                         // self loop: weight dinv[i]
      uint4 u = *(const uint4*)(hp + (size_t)i * HID + cg * 8);
      acc8s(a, u, di);
    }
    for (int j = 0; j < m; j += 4) {
      int4 q = *(const int4*)(csr_row + start + j);  // wave-uniform, aligned
      int s = (g == 0) ? q.x : (g == 1) ? q.y : (g == 2) ? q.z : q.w;
      if (j + g < m) {
        float dv = dinv[s];
        uint4 u = *(const uint4*)(hp + (size_t)s * HID + cg * 8);
        acc8s(a, u, dv);
      }
    }
#pragma unroll
    for (int k = 0; k < 8; ++k) {
      a[k] += __shfl_xor(a[k], 16);
      a[k] += __shfl_xor(a[k], 32);
    }
    int gb = batch[i];
    if (gb != cur_g) {                    // wave-uniform branch
      if (lane < 16) {
#pragma unroll
        for (int k = 0; k < 8; ++k)
          atomicMax(&pooled_bits[cur_g * HID + cg * 8 + k], __float_as_uint(rm[k]));
      }
#pragma unroll
      for (int k = 0; k < 8; ++k) rm[k] = 0.f;
      cur_g = gb;
    }
#pragma unroll
    for (int k = 0; k < 8; ++k)
      rm[k] = fmaxf(rm[k], fmaxf(fmaf(di, a[k], bv[k]), 0.f));
  }
  if (lane < 16) {
#pragma unroll
    for (int k = 0; k < 8; ++k)
      atomicMax(&pooled_bits[cur_g * HID + cg * 8 + k], __float_as_uint(rm[k]));
  }
}

// ---- logits = pooled @ lin_W + lin_b ----
__global__ void logits_k(const float* __restrict__ pooled, const float* __restrict__ lin_W,
                         const float* __restrict__ lin_b, float* __restrict__ out) {
  int t = blockIdx.x * blockDim.x + threadIdx.x;
  if (t < N_GRAPHS * NOUT) {
    int g = t >> 1, o = t & 1;
    float s = lin_b[o];
    const float* pg = pooled + g * HID;
#pragma unroll 8
    for (int k = 0; k < HID; ++k) s = fmaf(pg[k], lin_W[k * NOUT + o], s);
    out[t] = s;
  }
}

extern "C" void kernel_launch(void* const* d_in, const int* in_sizes, int n_in,
                              void* d_out, int out_size, void* d_ws, size_t ws_size,
                              hipStream_t stream) {
  (void)in_sizes; (void)n_in; (void)ws_size; (void)out_size;
  const float* x     = (const float*)d_in[0];
  const int*   ei    = (const int*)d_in[1];
  const int*   row   = ei;             // sources
  const int*   col   = ei + N_EDGES;   // targets
  const int*   batch = (const int*)d_in[2];
  const float* W     = (const float*)d_in[3];
  const float* b     = (const float*)d_in[4];
  const float* lin_W = (const float*)d_in[5];
  const float* lin_b = (const float*)d_in[6];
  float* out = (float*)d_out;
  float* pooled0 = out + N_GRAPHS * NOUT;

  // workspace layout, ~135.8 MB total (poison fill shows ws >= 640 MB)
  char* ws = (char*)d_ws;
  int*   bcnt    = (int*)(ws + 0);               //   4,096 B (391 used)
  int*   offs    = (int*)(ws + 4096);            // 400,000 B
  int*   cnt     = (int*)(ws + 404096);          // 400,000 B
  float* dinv    = (float*)(ws + 804096);        // 400,000 B
  unsigned short* Wf = (unsigned short*)(ws + 1204096);   // 106,496 B (frag order)
  int*   csr_row = (int*)(ws + 1310720);         // 12,812,288 B
  unsigned int* pairs = (unsigned int*)(ws + 14123008);   // 12,812,288 B
  unsigned short* hp  = (unsigned short*)(ws + 26935296); // 25,600,000 B
  unsigned short* xb  = (unsigned short*)(ws + 52535296); // 83,200,000 B bf16 x

  hipMemsetAsync(bcnt, 0, NBUCK * sizeof(int), stream);

  // L1: bucket-append || Wf pack + pooled zero || x->bf16 convert (streaming)
  prep_bucket_k<<<NBLK_BUCKET + NBLK_PREP + NBLK_XCONV, 256, 0, stream>>>(
      row, col, bcnt, pairs, W, Wf, x, xb, pooled0);
  // L2: CSR build (391) || GEMM with full-K register prefetch (782)
  csr_gemm_k<<<NBUCK + NBLK_GEMM, 512, 0, stream>>>(
      pairs, bcnt, csr_row, offs, cnt, dinv, xb, Wf, hp);
  // L3: gather (random-fabric floor ~94 us)
  {
    int waves = (N_NODES + NPW - 1) / NPW;             // 6250
    int blocks = (waves * 64 + 255) / 256;             // 1563
    gather_k<<<blocks, 256, 0, stream>>>(
        hp, csr_row, offs, cnt, dinv, batch, b,
        (unsigned int*)pooled0);
  }
  logits_k<<<(N_GRAPHS * NOUT + 255) / 256, 256, 0, stream>>>(
      pooled0, lin_W, lin_b, out);
}